// Round 3
// baseline (526.395 us; speedup 1.0000x reference)
//
#include <hip/hip_runtime.h>

typedef short short8 __attribute__((ext_vector_type(8)));
typedef short short4v __attribute__((ext_vector_type(4)));
typedef float f32x4 __attribute__((ext_vector_type(4)));
typedef unsigned short u16;

__device__ __forceinline__ u16 f2bf(float f) {
  unsigned int u = __builtin_bit_cast(unsigned int, f);
  u = (u + 0x7FFFu + ((u >> 16) & 1u)) >> 16;
  return (u16)u;
}
__device__ __forceinline__ float bf2f(u16 h) {
  unsigned int u = ((unsigned int)h) << 16;
  return __builtin_bit_cast(float, u);
}
__device__ __forceinline__ short8 cvt8(float4 a, float4 b) {
  short8 v;
  v[0] = (short)f2bf(a.x); v[1] = (short)f2bf(a.y);
  v[2] = (short)f2bf(a.z); v[3] = (short)f2bf(a.w);
  v[4] = (short)f2bf(b.x); v[5] = (short)f2bf(b.y);
  v[6] = (short)f2bf(b.z); v[7] = (short)f2bf(b.w);
  return v;
}
__device__ __forceinline__ short4v pack4(f32x4 a) {
  short4v v;
  v[0] = (short)f2bf(a[0]); v[1] = (short)f2bf(a[1]);
  v[2] = (short)f2bf(a[2]); v[3] = (short)f2bf(a[3]);
  return v;
}
__device__ __forceinline__ float sigmoidf_fast(float x) {
  return __builtin_amdgcn_rcpf(1.0f + __expf(-x));
}
__device__ __forceinline__ float tanhf_fast(float x) {
  return 1.0f - 2.0f * __builtin_amdgcn_rcpf(1.0f + __expf(2.0f * x));
}

#define NPX 147456  // 64*48*48

// ---------------------------------------------------------------------------
// K1: xg[dir][px][192] = x[px][:] @ W_dir^T + (bih+bhh), bf16.
// 9216 blocks (bid&3 = dir -> x-tile L2 reuse across dirs), 256 threads.
// One 64x192x192 tile per block; W frags in regs; 24.6 KB LDS; no inner loop.
// ---------------------------------------------------------------------------
__global__ __launch_bounds__(256)
void xg_gemm_kernel(const float* __restrict__ x,
    const float* __restrict__ w0, const float* __restrict__ w1,
    const float* __restrict__ w2, const float* __restrict__ w3,
    const float* __restrict__ bi0, const float* __restrict__ bh0,
    const float* __restrict__ bi1, const float* __restrict__ bh1,
    const float* __restrict__ bi2, const float* __restrict__ bh2,
    const float* __restrict__ bi3, const float* __restrict__ bh3,
    u16* __restrict__ xg)
{
  __shared__ u16 xl[12288];            // [64 px][192 k] bf16, XOR-swizzled
  const int tid  = threadIdx.x;
  const int lane = tid & 63;
  const int wv   = tid >> 6;           // 0..3 -> n-range 48*wv
  const int cl   = lane & 15;
  const int kg   = lane >> 4;
  const int dir  = blockIdx.x & 3;
  const int pxb  = (blockIdx.x >> 2) * 64;

  const float* wp  = dir == 0 ? w0 : dir == 1 ? w1 : dir == 2 ? w2 : w3;
  const float* bip = dir == 0 ? bi0 : dir == 1 ? bi1 : dir == 2 ? bi2 : bi3;
  const float* bhp = dir == 0 ? bh0 : dir == 1 ? bh1 : dir == 2 ? bh2 : bh3;

  // issue x loads first (HBM latency hides under W/bias L2 loads)
  float4 sa[6], sb[6];
  #pragma unroll
  for (int i = 0; i < 6; ++i) {
    int ch = tid + 256 * i;            // 0..1535
    int pxl = ch / 24;
    int k0  = (ch % 24) << 3;
    const float4* p = (const float4*)(x + (size_t)(pxb + pxl) * 192 + k0);
    sa[i] = p[0]; sb[i] = p[1];
  }

  // W fragments (A-operand): row n = wv*48 + nt*16 + cl, k = kk*32 + kg*8
  short8 wf[3][6];
  #pragma unroll
  for (int nt = 0; nt < 3; ++nt) {
    int n = wv * 48 + nt * 16 + cl;
    #pragma unroll
    for (int kk = 0; kk < 6; ++kk) {
      const float4* p = (const float4*)(wp + n * 192 + kk * 32 + kg * 8);
      wf[nt][kk] = cvt8(p[0], p[1]);
    }
  }
  // bias folded into acc init; D row = n = wv*48 + nt*16 + kg*4 + r
  f32x4 bv[3];
  #pragma unroll
  for (int nt = 0; nt < 3; ++nt)
    #pragma unroll
    for (int r = 0; r < 4; ++r) {
      int n = wv * 48 + nt * 16 + kg * 4 + r;
      bv[nt][r] = bip[n] + bhp[n];
    }

  #pragma unroll
  for (int i = 0; i < 6; ++i) {
    int ch = tid + 256 * i;
    int pxl = ch / 24;
    int k0  = (ch % 24) << 3;
    *(short8*)&xl[(pxl * 192 + k0) ^ ((pxl & 7) << 3)] = cvt8(sa[i], sb[i]);
  }
  __syncthreads();

  f32x4 acc[3][4];
  #pragma unroll
  for (int nt = 0; nt < 3; ++nt)
    #pragma unroll
    for (int mi = 0; mi < 4; ++mi) acc[nt][mi] = bv[nt];

  #pragma unroll
  for (int kk = 0; kk < 6; ++kk) {
    short8 bfr[4];
    #pragma unroll
    for (int mi = 0; mi < 4; ++mi) {
      int row = mi * 16 + cl;
      bfr[mi] = *(const short8*)&xl[(row * 192 + kk * 32 + kg * 8) ^ ((row & 7) << 3)];
    }
    #pragma unroll
    for (int nt = 0; nt < 3; ++nt)
      #pragma unroll
      for (int mi = 0; mi < 4; ++mi)
        acc[nt][mi] = __builtin_amdgcn_mfma_f32_16x16x32_bf16(wf[nt][kk], bfr[mi], acc[nt][mi], 0, 0, 0);
  }

  #pragma unroll
  for (int nt = 0; nt < 3; ++nt)
    #pragma unroll
    for (int mi = 0; mi < 4; ++mi) {
      int px = pxb + mi * 16 + cl;
      size_t o = ((size_t)dir * NPX + px) * 192 + wv * 48 + nt * 16 + kg * 4;
      *(short4v*)(xg + o) = pack4(acc[nt][mi]);
    }
}

// ---------------------------------------------------------------------------
// K2: recurrent scan. 1536 single-wave blocks; each wave owns 8 sequences
// (B cols 0..7 valid, 8..15 dummy) -> 6 waves/CU. whh in regs; h via 2.3 KB
// LDS strip; xg 2-step ping-pong register prefetch.
// ---------------------------------------------------------------------------
__global__ __launch_bounds__(64)
void scan_kernel(const u16* __restrict__ xg,
    const float* __restrict__ u0, const float* __restrict__ u1,
    const float* __restrict__ u2, const float* __restrict__ u3,
    u16* __restrict__ comb)
{
  __shared__ u16 hl[1152];             // [16 seq][72] (48 h + 24 zero pad)
  const int lane = threadIdx.x;
  const int cl   = lane & 15;
  const int kg   = lane >> 4;
  const int W    = blockIdx.x;         // 0..1535
  const int dir  = W / 384;
  const int g    = W - dir * 384;
  const int bb   = g / 6;
  const int rcr  = (g - bb * 6) * 8 + cl;
  const int rc   = rcr < 48 ? rcr : 47;   // clamp for dummy lanes' loads
  const bool vert = dir < 2;
  const bool bwd  = (dir & 1) != 0;
  const bool live = cl < 8;

  const float* up = dir == 0 ? u0 : dir == 1 ? u1 : dir == 2 ? u2 : u3;

  const int tp0 = bwd ? 47 : 0;
  int px = vert ? (bb * 48 + tp0) * 48 + rc : (bb * 48 + rc) * 48 + tp0;
  const int dpx = (vert ? 48 : 1) * (bwd ? -1 : 1);
  const u16* xgd = xg + (size_t)dir * NPX * 192 + kg * 4;

  // issue t=0 / t=1 prefetches first (under the whh L2 loads)
  short4v xbA[12], xbB[12];
  {
    const u16* xp = xgd + (size_t)px * 192;
    #pragma unroll
    for (int nt = 0; nt < 12; ++nt) xbA[nt] = *(const short4v*)(xp + nt * 16);
    const u16* xq = xgd + (size_t)(px + dpx) * 192;
    #pragma unroll
    for (int nt = 0; nt < 12; ++nt) xbB[nt] = *(const short4v*)(xq + nt * 16);
  }

  // whh fragments (A-operand), K padded 48->64; zeros for k>=48
  short8 uf[12][2];
  #pragma unroll
  for (int nt = 0; nt < 12; ++nt) {
    int n = nt * 16 + cl;
    {
      const float4* p = (const float4*)(up + n * 48 + kg * 8);
      uf[nt][0] = cvt8(p[0], p[1]);
    }
    if (kg < 2) {
      const float4* p = (const float4*)(up + n * 48 + 32 + kg * 8);
      uf[nt][1] = cvt8(p[0], p[1]);
    } else {
      short8 z = {}; uf[nt][1] = z;
    }
  }

  // zero h strip (t=0 sees h=0; pad stays zero)
  #pragma unroll
  for (int i = 0; i < 18; ++i) hl[lane * 18 + i] = 0;

  float c[12];
  #pragma unroll
  for (int i = 0; i < 12; ++i) c[i] = 0.f;

  auto step = [&](short4v (&xb)[12], int pxc, int pxf, bool pf) {
    short8 hb0 = *(const short8*)&hl[cl * 72 + kg * 8];
    short8 hb1 = *(const short8*)&hl[cl * 72 + 32 + kg * 8];

    f32x4 acc[12];
    #pragma unroll
    for (int nt = 0; nt < 12; ++nt) {
      f32x4 a;
      a[0] = bf2f((u16)xb[nt][0]); a[1] = bf2f((u16)xb[nt][1]);
      a[2] = bf2f((u16)xb[nt][2]); a[3] = bf2f((u16)xb[nt][3]);
      acc[nt] = a;
    }
    // refill this buffer for t+2 immediately (2-step latency cover)
    if (pf) {
      const u16* xp = xgd + (size_t)pxf * 192;
      #pragma unroll
      for (int nt = 0; nt < 12; ++nt) xb[nt] = *(const short4v*)(xp + nt * 16);
    }
    #pragma unroll
    for (int nt = 0; nt < 12; ++nt)
      acc[nt] = __builtin_amdgcn_mfma_f32_16x16x32_bf16(uf[nt][0], hb0, acc[nt], 0, 0, 0);
    #pragma unroll
    for (int nt = 0; nt < 12; ++nt)
      acc[nt] = __builtin_amdgcn_mfma_f32_16x16x32_bf16(uf[nt][1], hb1, acc[nt], 0, 0, 0);

    #pragma unroll
    for (int q = 0; q < 3; ++q) {
      short4v h4;
      #pragma unroll
      for (int r = 0; r < 4; ++r) {
        float xi  = acc[q][r];
        float xf  = acc[3 + q][r];
        float xgv = acc[6 + q][r];
        float xo  = acc[9 + q][r];
        float ii = sigmoidf_fast(xi);
        float ff = sigmoidf_fast(xf);
        float gg = tanhf_fast(xgv);
        float oo = sigmoidf_fast(xo);
        float cc = ff * c[q * 4 + r] + ii * gg;
        c[q * 4 + r] = cc;
        float hh = oo * tanhf_fast(cc);
        h4[r] = (short)f2bf(hh);
      }
      *(short4v*)&hl[cl * 72 + q * 16 + kg * 4] = h4;
      if (live)
        *(short4v*)&comb[(size_t)pxc * 192 + dir * 48 + q * 16 + kg * 4] = h4;
    }
  };

  for (int it = 0; it < 24; ++it) {
    step(xbA, px, px + 2 * dpx, it < 23);
    px += dpx;
    step(xbB, px, px + 2 * dpx, it < 23);
    px += dpx;
  }
}

// ---------------------------------------------------------------------------
// K3: out[px][c] = comb[px][:] @ proj_w[c][:] + proj_b[c], fp32.
// K1-style: 2304 blocks, 256 threads, pw frags in regs, 24.6 KB LDS.
// ---------------------------------------------------------------------------
__global__ __launch_bounds__(256)
void proj_kernel(const u16* __restrict__ comb,
                 const float* __restrict__ pw,
                 const float* __restrict__ pb,
                 float* __restrict__ out)
{
  __shared__ u16 al[12288];            // [64 px][192 k] bf16, swizzled
  const int tid  = threadIdx.x;
  const int lane = tid & 63;
  const int wv   = tid >> 6;
  const int cl   = lane & 15;
  const int kg   = lane >> 4;
  const int pxb  = blockIdx.x * 64;

  // stage comb tile (bf16 direct)
  #pragma unroll
  for (int i = 0; i < 6; ++i) {
    int ch = tid + 256 * i;
    int pxl = ch / 24;
    int k0  = (ch % 24) << 3;
    short8 v = *(const short8*)(comb + (size_t)(pxb + pxl) * 192 + k0);
    *(short8*)&al[(pxl * 192 + k0) ^ ((pxl & 7) << 3)] = v;
  }

  // pw fragments: row c = wv*48 + nt*16 + cl
  short8 wf[3][6];
  #pragma unroll
  for (int nt = 0; nt < 3; ++nt) {
    int n = wv * 48 + nt * 16 + cl;
    #pragma unroll
    for (int kk = 0; kk < 6; ++kk) {
      const float4* p = (const float4*)(pw + n * 192 + kk * 32 + kg * 8);
      wf[nt][kk] = cvt8(p[0], p[1]);
    }
  }
  f32x4 bv[3];
  #pragma unroll
  for (int nt = 0; nt < 3; ++nt)
    #pragma unroll
    for (int r = 0; r < 4; ++r)
      bv[nt][r] = pb[wv * 48 + nt * 16 + kg * 4 + r];

  __syncthreads();

  f32x4 acc[3][4];
  #pragma unroll
  for (int nt = 0; nt < 3; ++nt)
    #pragma unroll
    for (int mi = 0; mi < 4; ++mi) acc[nt][mi] = bv[nt];

  #pragma unroll
  for (int kk = 0; kk < 6; ++kk) {
    short8 bfr[4];
    #pragma unroll
    for (int mi = 0; mi < 4; ++mi) {
      int row = mi * 16 + cl;
      bfr[mi] = *(const short8*)&al[(row * 192 + kk * 32 + kg * 8) ^ ((row & 7) << 3)];
    }
    #pragma unroll
    for (int nt = 0; nt < 3; ++nt)
      #pragma unroll
      for (int mi = 0; mi < 4; ++mi)
        acc[nt][mi] = __builtin_amdgcn_mfma_f32_16x16x32_bf16(wf[nt][kk], bfr[mi], acc[nt][mi], 0, 0, 0);
  }

  #pragma unroll
  for (int nt = 0; nt < 3; ++nt)
    #pragma unroll
    for (int mi = 0; mi < 4; ++mi) {
      size_t o = (size_t)(pxb + mi * 16 + cl) * 192 + wv * 48 + nt * 16 + kg * 4;
      *(f32x4*)(out + o) = acc[nt][mi];
    }
}

extern "C" void kernel_launch(void* const* d_in, const int* in_sizes, int n_in,
                              void* d_out, int out_size, void* d_ws, size_t ws_size,
                              hipStream_t stream) {
  const float* x = (const float*)d_in[0];
  u16* xg   = (u16*)d_ws;                              // 4*147456*192*2B = 226.5 MB
  u16* comb = (u16*)d_ws + (size_t)4 * NPX * 192;      // + 56.6 MB

  xg_gemm_kernel<<<9216, 256, 0, stream>>>(
      x,
      (const float*)d_in[1], (const float*)d_in[5],
      (const float*)d_in[9], (const float*)d_in[13],
      (const float*)d_in[3],  (const float*)d_in[4],
      (const float*)d_in[7],  (const float*)d_in[8],
      (const float*)d_in[11], (const float*)d_in[12],
      (const float*)d_in[15], (const float*)d_in[16],
      xg);

  scan_kernel<<<1536, 64, 0, stream>>>(
      xg,
      (const float*)d_in[2], (const float*)d_in[6],
      (const float*)d_in[10], (const float*)d_in[14],
      comb);

  proj_kernel<<<2304, 256, 0, stream>>>(
      comb, (const float*)d_in[17], (const float*)d_in[18], (float*)d_out);
}

// Round 4
// 364.725 us; speedup vs baseline: 1.4433x; 1.4433x over previous
//
#include <hip/hip_runtime.h>

typedef short short8 __attribute__((ext_vector_type(8)));
typedef short short4v __attribute__((ext_vector_type(4)));
typedef float f32x4 __attribute__((ext_vector_type(4)));
typedef unsigned short u16;

__device__ __forceinline__ u16 f2bf(float f) {
  unsigned int u = __builtin_bit_cast(unsigned int, f);
  u = (u + 0x7FFFu + ((u >> 16) & 1u)) >> 16;
  return (u16)u;
}
__device__ __forceinline__ float bf2f(u16 h) {
  unsigned int u = ((unsigned int)h) << 16;
  return __builtin_bit_cast(float, u);
}
__device__ __forceinline__ short8 cvt8(float4 a, float4 b) {
  short8 v;
  v[0] = (short)f2bf(a.x); v[1] = (short)f2bf(a.y);
  v[2] = (short)f2bf(a.z); v[3] = (short)f2bf(a.w);
  v[4] = (short)f2bf(b.x); v[5] = (short)f2bf(b.y);
  v[6] = (short)f2bf(b.z); v[7] = (short)f2bf(b.w);
  return v;
}
__device__ __forceinline__ short4v pack4(f32x4 a) {
  short4v v;
  v[0] = (short)f2bf(a[0]); v[1] = (short)f2bf(a[1]);
  v[2] = (short)f2bf(a[2]); v[3] = (short)f2bf(a[3]);
  return v;
}
__device__ __forceinline__ float sigmoidf_fast(float x) {
  return __builtin_amdgcn_rcpf(1.0f + __expf(-x));
}
__device__ __forceinline__ float tanhf_fast(float x) {
  return 1.0f - 2.0f * __builtin_amdgcn_rcpf(1.0f + __expf(2.0f * x));
}

#define NPX 147456  // 64*48*48

// ---------------------------------------------------------------------------
// K1: xg[dir][px][192] = x[px][:] @ W_dir^T + (bih+bhh), bf16.
// 9216 blocks, 256 threads. XCD-bijective swizzle: the 4 dir-blocks of one
// px-tile share an XCD (bid = 8*j + xcd; dir = j&3; px_tile = (j>>2)*8+xcd)
// -> x-tile fetched once from HBM, reused in that XCD's L2.
// ---------------------------------------------------------------------------
__global__ __launch_bounds__(256)
void xg_gemm_kernel(const float* __restrict__ x,
    const float* __restrict__ w0, const float* __restrict__ w1,
    const float* __restrict__ w2, const float* __restrict__ w3,
    const float* __restrict__ bi0, const float* __restrict__ bh0,
    const float* __restrict__ bi1, const float* __restrict__ bh1,
    const float* __restrict__ bi2, const float* __restrict__ bh2,
    const float* __restrict__ bi3, const float* __restrict__ bh3,
    u16* __restrict__ xg)
{
  __shared__ u16 xl[12288];            // [64 px][192 k] bf16, XOR-swizzled
  const int tid  = threadIdx.x;
  const int lane = tid & 63;
  const int wv   = tid >> 6;           // 0..3 -> n-range 48*wv
  const int cl   = lane & 15;
  const int kg   = lane >> 4;
  const int xcd  = blockIdx.x & 7;
  const int j    = blockIdx.x >> 3;    // 0..1151
  const int dir  = j & 3;
  const int pxb  = ((j >> 2) * 8 + xcd) * 64;

  const float* wp  = dir == 0 ? w0 : dir == 1 ? w1 : dir == 2 ? w2 : w3;
  const float* bip = dir == 0 ? bi0 : dir == 1 ? bi1 : dir == 2 ? bi2 : bi3;
  const float* bhp = dir == 0 ? bh0 : dir == 1 ? bh1 : dir == 2 ? bh2 : bh3;

  // issue x loads first (HBM latency hides under W/bias L2 loads)
  float4 sa[6], sb[6];
  #pragma unroll
  for (int i = 0; i < 6; ++i) {
    int ch = tid + 256 * i;            // 0..1535
    int pxl = ch / 24;
    int k0  = (ch % 24) << 3;
    const float4* p = (const float4*)(x + (size_t)(pxb + pxl) * 192 + k0);
    sa[i] = p[0]; sb[i] = p[1];
  }

  // W fragments (A-operand): row n = wv*48 + nt*16 + cl, k = kk*32 + kg*8
  short8 wf[3][6];
  #pragma unroll
  for (int nt = 0; nt < 3; ++nt) {
    int n = wv * 48 + nt * 16 + cl;
    #pragma unroll
    for (int kk = 0; kk < 6; ++kk) {
      const float4* p = (const float4*)(wp + n * 192 + kk * 32 + kg * 8);
      wf[nt][kk] = cvt8(p[0], p[1]);
    }
  }
  // bias folded into acc init; D row n = wv*48 + nt*16 + kg*4 + r
  f32x4 bv[3];
  #pragma unroll
  for (int nt = 0; nt < 3; ++nt)
    #pragma unroll
    for (int r = 0; r < 4; ++r) {
      int n = wv * 48 + nt * 16 + kg * 4 + r;
      bv[nt][r] = bip[n] + bhp[n];
    }

  #pragma unroll
  for (int i = 0; i < 6; ++i) {
    int ch = tid + 256 * i;
    int pxl = ch / 24;
    int k0  = (ch % 24) << 3;
    *(short8*)&xl[(pxl * 192 + k0) ^ ((pxl & 7) << 3)] = cvt8(sa[i], sb[i]);
  }
  __syncthreads();

  f32x4 acc[3][4];
  #pragma unroll
  for (int nt = 0; nt < 3; ++nt)
    #pragma unroll
    for (int mi = 0; mi < 4; ++mi) acc[nt][mi] = bv[nt];

  #pragma unroll
  for (int kk = 0; kk < 6; ++kk) {
    short8 bfr[4];
    #pragma unroll
    for (int mi = 0; mi < 4; ++mi) {
      int row = mi * 16 + cl;
      bfr[mi] = *(const short8*)&xl[(row * 192 + kk * 32 + kg * 8) ^ ((row & 7) << 3)];
    }
    #pragma unroll
    for (int nt = 0; nt < 3; ++nt)
      #pragma unroll
      for (int mi = 0; mi < 4; ++mi)
        acc[nt][mi] = __builtin_amdgcn_mfma_f32_16x16x32_bf16(wf[nt][kk], bfr[mi], acc[nt][mi], 0, 0, 0);
  }

  #pragma unroll
  for (int nt = 0; nt < 3; ++nt)
    #pragma unroll
    for (int mi = 0; mi < 4; ++mi) {
      int px = pxb + mi * 16 + cl;
      size_t o = ((size_t)dir * NPX + px) * 192 + wv * 48 + nt * 16 + kg * 4;
      *(short4v*)(xg + o) = pack4(acc[nt][mi]);
    }
}

// ---------------------------------------------------------------------------
// K2: recurrent scan. 768 blocks x 3 waves (192 thr); block owns 16 seqs of
// one direction; wave wv owns hd-slice [16wv,16wv+16) = gate tiles
// {wv, wv+3, wv+6, wv+9}: 4 accs, 8 MFMAs, 4-iter epilogue per step.
// h double-buffered in LDS (1 barrier/step); xg 4-deep register prefetch ring.
// ---------------------------------------------------------------------------
__global__ __launch_bounds__(192)
void scan_kernel(const u16* __restrict__ xg,
    const float* __restrict__ u0, const float* __restrict__ u1,
    const float* __restrict__ u2, const float* __restrict__ u3,
    u16* __restrict__ comb)
{
  __shared__ u16 hl[2][1152];          // [16 seq][72] (48 h + 24 zero pad)
  const int tid  = threadIdx.x;
  const int lane = tid & 63;
  const int wv   = tid >> 6;           // 0..2
  const int cl   = lane & 15;
  const int kg   = lane >> 4;
  const int W    = blockIdx.x;         // 0..767
  const int dir  = W / 192;
  const int g    = W - dir * 192;
  const int bb   = g / 3;
  const int rc   = (g - bb * 3) * 16 + cl;
  const bool vert = dir < 2;
  const bool bwd  = (dir & 1) != 0;

  const float* up = dir == 0 ? u0 : dir == 1 ? u1 : dir == 2 ? u2 : u3;

  const int tp0 = bwd ? 47 : 0;
  int px = vert ? (bb * 48 + tp0) * 48 + rc : (bb * 48 + rc) * 48 + tp0;
  const int dpx = (vert ? 48 : 1) * (bwd ? -1 : 1);
  const u16* xgd = xg + (size_t)dir * NPX * 192 + wv * 16 + kg * 4;

  // 4-deep prefetch ring: slot s holds xg for step t (t mod 4 == s).
  // (Overrun prefetches at t>=48 read garbage inside the xg buffer; never
  // consumed — bounds verified for all 4 directions.)
  short4v xb[4][4];
  #pragma unroll
  for (int s = 0; s < 4; ++s) {
    const u16* xp = xgd + (size_t)(px + s * dpx) * 192;
    #pragma unroll
    for (int q = 0; q < 4; ++q)
      xb[s][q] = *(const short4v*)(xp + q * 48);
  }

  // whh fragments (A-operand) for gate tiles q*3+wv; K padded 48->64
  short8 uf[4][2];
  #pragma unroll
  for (int q = 0; q < 4; ++q) {
    int n = q * 48 + wv * 16 + cl;
    {
      const float4* p = (const float4*)(up + n * 48 + kg * 8);
      uf[q][0] = cvt8(p[0], p[1]);
    }
    if (kg < 2) {
      const float4* p = (const float4*)(up + n * 48 + 32 + kg * 8);
      uf[q][1] = cvt8(p[0], p[1]);
    } else {
      short8 z = {}; uf[q][1] = z;
    }
  }

  // zero both h buffers (incl. pad) -> t=0 sees h=0, pads stay zero
  u16* hz = &hl[0][0];
  for (int i = tid; i < 2304; i += 192) hz[i] = 0;
  __syncthreads();

  float c[4] = {0.f, 0.f, 0.f, 0.f};
  int cur = 0;
  u16* cb = comb + (size_t)dir * NPX * 48 + wv * 16 + kg * 4;

  for (int it = 0; it < 12; ++it) {
    #pragma unroll
    for (int u = 0; u < 4; ++u) {
      short8 hb0 = *(const short8*)&hl[cur][cl * 72 + kg * 8];
      short8 hb1 = *(const short8*)&hl[cur][cl * 72 + 32 + kg * 8];

      f32x4 acc[4];
      #pragma unroll
      for (int q = 0; q < 4; ++q) {
        f32x4 a;
        a[0] = bf2f((u16)xb[u][q][0]); a[1] = bf2f((u16)xb[u][q][1]);
        a[2] = bf2f((u16)xb[u][q][2]); a[3] = bf2f((u16)xb[u][q][3]);
        acc[q] = a;
      }
      // refill slot u for step t+4 (issue early; ~4-step latency cover)
      {
        const u16* xp = xgd + (size_t)(px + 4 * dpx) * 192;
        #pragma unroll
        for (int q = 0; q < 4; ++q)
          xb[u][q] = *(const short4v*)(xp + q * 48);
      }
      #pragma unroll
      for (int q = 0; q < 4; ++q)
        acc[q] = __builtin_amdgcn_mfma_f32_16x16x32_bf16(uf[q][0], hb0, acc[q], 0, 0, 0);
      #pragma unroll
      for (int q = 0; q < 4; ++q)
        acc[q] = __builtin_amdgcn_mfma_f32_16x16x32_bf16(uf[q][1], hb1, acc[q], 0, 0, 0);

      // epilogue: lane -> seq=cl, hd = wv*16 + kg*4 + r
      short4v h4;
      #pragma unroll
      for (int r = 0; r < 4; ++r) {
        float ii = sigmoidf_fast(acc[0][r]);
        float ff = sigmoidf_fast(acc[1][r]);
        float gg = tanhf_fast(acc[2][r]);
        float oo = sigmoidf_fast(acc[3][r]);
        float cc = ff * c[r] + ii * gg;
        c[r] = cc;
        h4[r] = (short)f2bf(oo * tanhf_fast(cc));
      }
      *(short4v*)&hl[cur ^ 1][cl * 72 + wv * 16 + kg * 4] = h4;
      *(short4v*)(cb + (size_t)px * 48) = h4;
      __syncthreads();
      cur ^= 1;
      px += dpx;
    }
  }
}

// ---------------------------------------------------------------------------
// K3: out[px][c] = comb4[px][:] @ proj_w[c][:] + proj_b[c], fp32.
// comb layout [dir][px][48]; 8-elt staging chunks never cross dir boundary.
// ---------------------------------------------------------------------------
__global__ __launch_bounds__(256)
void proj_kernel(const u16* __restrict__ comb,
                 const float* __restrict__ pw,
                 const float* __restrict__ pb,
                 float* __restrict__ out)
{
  __shared__ u16 al[12288];            // [64 px][192 k] bf16, swizzled
  const int tid  = threadIdx.x;
  const int lane = tid & 63;
  const int wv   = tid >> 6;
  const int cl   = lane & 15;
  const int kg   = lane >> 4;
  const int pxb  = blockIdx.x * 64;

  // stage comb tile: k = dir*48 + off
  #pragma unroll
  for (int i = 0; i < 6; ++i) {
    int ch = tid + 256 * i;
    int pxl = ch / 24;
    int k0  = (ch % 24) << 3;
    int d   = k0 / 48;
    short8 v = *(const short8*)(comb + ((size_t)d * NPX + pxb + pxl) * 48 + (k0 - d * 48));
    *(short8*)&al[(pxl * 192 + k0) ^ ((pxl & 7) << 3)] = v;
  }

  // pw fragments: row c = wv*48 + nt*16 + cl
  short8 wf[3][6];
  #pragma unroll
  for (int nt = 0; nt < 3; ++nt) {
    int n = wv * 48 + nt * 16 + cl;
    #pragma unroll
    for (int kk = 0; kk < 6; ++kk) {
      const float4* p = (const float4*)(pw + n * 192 + kk * 32 + kg * 8);
      wf[nt][kk] = cvt8(p[0], p[1]);
    }
  }
  f32x4 bv[3];
  #pragma unroll
  for (int nt = 0; nt < 3; ++nt)
    #pragma unroll
    for (int r = 0; r < 4; ++r)
      bv[nt][r] = pb[wv * 48 + nt * 16 + kg * 4 + r];

  __syncthreads();

  f32x4 acc[3][4];
  #pragma unroll
  for (int nt = 0; nt < 3; ++nt)
    #pragma unroll
    for (int mi = 0; mi < 4; ++mi) acc[nt][mi] = bv[nt];

  #pragma unroll
  for (int kk = 0; kk < 6; ++kk) {
    short8 bfr[4];
    #pragma unroll
    for (int mi = 0; mi < 4; ++mi) {
      int row = mi * 16 + cl;
      bfr[mi] = *(const short8*)&al[(row * 192 + kk * 32 + kg * 8) ^ ((row & 7) << 3)];
    }
    #pragma unroll
    for (int nt = 0; nt < 3; ++nt)
      #pragma unroll
      for (int mi = 0; mi < 4; ++mi)
        acc[nt][mi] = __builtin_amdgcn_mfma_f32_16x16x32_bf16(wf[nt][kk], bfr[mi], acc[nt][mi], 0, 0, 0);
  }

  #pragma unroll
  for (int nt = 0; nt < 3; ++nt)
    #pragma unroll
    for (int mi = 0; mi < 4; ++mi) {
      size_t o = (size_t)(pxb + mi * 16 + cl) * 192 + wv * 48 + nt * 16 + kg * 4;
      *(f32x4*)(out + o) = acc[nt][mi];
    }
}

extern "C" void kernel_launch(void* const* d_in, const int* in_sizes, int n_in,
                              void* d_out, int out_size, void* d_ws, size_t ws_size,
                              hipStream_t stream) {
  const float* x = (const float*)d_in[0];
  u16* xg   = (u16*)d_ws;                              // 4*147456*192*2B = 226.5 MB
  u16* comb = (u16*)d_ws + (size_t)4 * NPX * 192;      // 4*147456*48*2B = 56.6 MB

  xg_gemm_kernel<<<9216, 256, 0, stream>>>(
      x,
      (const float*)d_in[1], (const float*)d_in[5],
      (const float*)d_in[9], (const float*)d_in[13],
      (const float*)d_in[3],  (const float*)d_in[4],
      (const float*)d_in[7],  (const float*)d_in[8],
      (const float*)d_in[11], (const float*)d_in[12],
      (const float*)d_in[15], (const float*)d_in[16],
      xg);

  scan_kernel<<<768, 192, 0, stream>>>(
      xg,
      (const float*)d_in[2], (const float*)d_in[6],
      (const float*)d_in[10], (const float*)d_in[14],
      comb);

  proj_kernel<<<2304, 256, 0, stream>>>(
      comb, (const float*)d_in[17], (const float*)d_in[18], (float*)d_out);
}

// Round 5
// 315.942 us; speedup vs baseline: 1.6661x; 1.1544x over previous
//
#include <hip/hip_runtime.h>

typedef short short8 __attribute__((ext_vector_type(8)));
typedef short short4v __attribute__((ext_vector_type(4)));
typedef float f32x4 __attribute__((ext_vector_type(4)));
typedef unsigned short u16;

__device__ __forceinline__ u16 f2bf(float f) {
  unsigned int u = __builtin_bit_cast(unsigned int, f);
  u = (u + 0x7FFFu + ((u >> 16) & 1u)) >> 16;
  return (u16)u;
}
__device__ __forceinline__ float bf2f(u16 h) {
  unsigned int u = ((unsigned int)h) << 16;
  return __builtin_bit_cast(float, u);
}
__device__ __forceinline__ short8 cvt8(float4 a, float4 b) {
  short8 v;
  v[0] = (short)f2bf(a.x); v[1] = (short)f2bf(a.y);
  v[2] = (short)f2bf(a.z); v[3] = (short)f2bf(a.w);
  v[4] = (short)f2bf(b.x); v[5] = (short)f2bf(b.y);
  v[6] = (short)f2bf(b.z); v[7] = (short)f2bf(b.w);
  return v;
}
__device__ __forceinline__ short4v pack4(f32x4 a) {
  short4v v;
  v[0] = (short)f2bf(a[0]); v[1] = (short)f2bf(a[1]);
  v[2] = (short)f2bf(a[2]); v[3] = (short)f2bf(a[3]);
  return v;
}
__device__ __forceinline__ float sigmoidf_fast(float x) {
  return __builtin_amdgcn_rcpf(1.0f + __expf(-x));
}
__device__ __forceinline__ float tanhf_fast(float x) {
  return 1.0f - 2.0f * __builtin_amdgcn_rcpf(1.0f + __expf(2.0f * x));
}
__device__ __forceinline__ void gload_lds16(const void* g, void* l) {
  __builtin_amdgcn_global_load_lds(
      (const __attribute__((address_space(1))) void*)g,
      (__attribute__((address_space(3))) void*)l, 16, 0, 0);
}

#define NPX 147456  // 64*48*48
#define NTILES 2304 // NPX/64

// ---------------------------------------------------------------------------
// K0: x fp32 -> xbf bf16, per-64px-tile, pre-XOR-swizzled (the exact LDS
// image K1 wants, so K1 can global_load_lds it linearly).
// ---------------------------------------------------------------------------
__global__ __launch_bounds__(256)
void xcvt_kernel(const float* __restrict__ x, u16* __restrict__ xbf)
{
  const int tile = blockIdx.x;
  const int tid  = threadIdx.x;
  const float* src = x + (size_t)tile * 12288;
  u16* dst = xbf + (size_t)tile * 12288;
  #pragma unroll
  for (int r = 0; r < 6; ++r) {
    int c   = r * 256 + tid;           // 8-elem chunk id, 0..1535
    int px  = c / 24;
    int k0  = (c % 24) << 3;
    const float4* p = (const float4*)(src + c * 8);
    *(short8*)&dst[(px * 192 + k0) ^ ((px & 7) << 3)] = cvt8(p[0], p[1]);
  }
}

// ---------------------------------------------------------------------------
// K1: xg[dir][px][192] = x[px][:] @ W_dir^T + (bih+bhh), bf16.
// 1152 blocks x 8 tiles; W frags in regs ONCE per block; x via global_load_lds
// (double-buffered, counted vmcnt(6) across raw barriers); D bounced through
// LDS for fully coalesced 16-B stores. XCD-bijective: 4 dir-blocks of one
// slice share an XCD (bid=8j+xcd; dir=j&3; slice=(j>>2)*8+xcd).
// ---------------------------------------------------------------------------
__global__ __launch_bounds__(256, 3)
void xg_gemm_kernel(const u16* __restrict__ xbf,
    const float* __restrict__ w0, const float* __restrict__ w1,
    const float* __restrict__ w2, const float* __restrict__ w3,
    const float* __restrict__ bi0, const float* __restrict__ bh0,
    const float* __restrict__ bi1, const float* __restrict__ bh1,
    const float* __restrict__ bi2, const float* __restrict__ bh2,
    const float* __restrict__ bi3, const float* __restrict__ bh3,
    u16* __restrict__ xg)
{
  __shared__ u16 xl[2][12288];         // double-buffered 64x192 bf16 tile (48 KB)
  const int tid  = threadIdx.x;
  const int lane = tid & 63;
  const int wv   = tid >> 6;           // 0..3 -> n-range 48*wv
  const int cl   = lane & 15;
  const int kg   = lane >> 4;
  const int xcd  = blockIdx.x & 7;
  const int j    = blockIdx.x >> 3;    // 0..143
  const int dir  = j & 3;
  const int slice = (j >> 2) * 8 + xcd; // 0..287
  const int tile0 = slice * 8;

  const float* wp  = dir == 0 ? w0 : dir == 1 ? w1 : dir == 2 ? w2 : w3;
  const float* bip = dir == 0 ? bi0 : dir == 1 ? bi1 : dir == 2 ? bi2 : bi3;
  const float* bhp = dir == 0 ? bh0 : dir == 1 ? bh1 : dir == 2 ? bh2 : bh3;

  // issue tile 0 loads immediately (in flight under W/bias setup)
  {
    const u16* src = xbf + (size_t)tile0 * 12288 + tid * 8;
    #pragma unroll
    for (int r = 0; r < 6; ++r)
      gload_lds16(src + r * 2048, &xl[0][r * 2048 + wv * 512]);
  }

  // W fragments (A-operand): row n = wv*48 + nt*16 + cl, k = kk*32 + kg*8
  short8 wf[3][6];
  #pragma unroll
  for (int nt = 0; nt < 3; ++nt) {
    int n = wv * 48 + nt * 16 + cl;
    #pragma unroll
    for (int kk = 0; kk < 6; ++kk) {
      const float4* p = (const float4*)(wp + n * 192 + kk * 32 + kg * 8);
      wf[nt][kk] = cvt8(p[0], p[1]);
    }
  }
  f32x4 bv[3];
  #pragma unroll
  for (int nt = 0; nt < 3; ++nt)
    #pragma unroll
    for (int r = 0; r < 4; ++r) {
      int n = wv * 48 + nt * 16 + kg * 4 + r;
      bv[nt][r] = bip[n] + bhp[n];
    }

  for (int t = 0; t < 8; ++t) {
    const int cur = t & 1;
    if (t < 7) {
      const u16* src = xbf + (size_t)(tile0 + t + 1) * 12288 + tid * 8;
      #pragma unroll
      for (int r = 0; r < 6; ++r)
        gload_lds16(src + r * 2048, &xl[cur ^ 1][r * 2048 + wv * 512]);
      __builtin_amdgcn_s_waitcnt(0xF76);   // vmcnt(6): cur tile landed, next in flight
    } else {
      __builtin_amdgcn_s_waitcnt(0xF70);   // vmcnt(0)
    }
    __builtin_amdgcn_s_barrier();          // bar1: xl[cur] ready
    __builtin_amdgcn_sched_barrier(0);

    f32x4 acc[3][4];
    #pragma unroll
    for (int nt = 0; nt < 3; ++nt)
      #pragma unroll
      for (int mi = 0; mi < 4; ++mi) acc[nt][mi] = bv[nt];

    #pragma unroll
    for (int kk = 0; kk < 6; ++kk) {
      short8 bfr[4];
      #pragma unroll
      for (int mi = 0; mi < 4; ++mi) {
        int row = mi * 16 + cl;
        bfr[mi] = *(const short8*)&xl[cur][(row * 192 + kk * 32 + kg * 8) ^ ((row & 7) << 3)];
      }
      #pragma unroll
      for (int nt = 0; nt < 3; ++nt)
        #pragma unroll
        for (int mi = 0; mi < 4; ++mi)
          acc[nt][mi] = __builtin_amdgcn_mfma_f32_16x16x32_bf16(wf[nt][kk], bfr[mi], acc[nt][mi], 0, 0, 0);
    }
    __builtin_amdgcn_s_barrier();          // bar2: all frag reads of xl[cur] done
    __builtin_amdgcn_sched_barrier(0);

    // D bounce into xl[cur] (bf16, swizzled)
    #pragma unroll
    for (int nt = 0; nt < 3; ++nt)
      #pragma unroll
      for (int mi = 0; mi < 4; ++mi) {
        int px = mi * 16 + cl;
        int nn = wv * 48 + nt * 16 + kg * 4;
        *(short4v*)&xl[cur][(px * 192 + nn) ^ ((px & 7) << 3)] = pack4(acc[nt][mi]);
      }
    __builtin_amdgcn_s_waitcnt(0xC07F);    // lgkmcnt(0): D writes landed
    __builtin_amdgcn_s_barrier();          // bar3
    __builtin_amdgcn_sched_barrier(0);

    // coalesced store: 16 B/thread x 6 rounds, contiguous 24 KB
    u16* dst = xg + ((size_t)dir * NPX + (size_t)(tile0 + t) * 64) * 192;
    #pragma unroll
    for (int r = 0; r < 6; ++r) {
      int c  = r * 256 + tid;
      int px = c / 24;
      int kc = (c % 24) << 3;
      short8 v = *(const short8*)&xl[cur][(px * 192 + kc) ^ ((px & 7) << 3)];
      *(short8*)(dst + c * 8) = v;
    }
    __builtin_amdgcn_s_barrier();          // bar4: bounce reads done before overwrite
    __builtin_amdgcn_sched_barrier(0);
  }
}

// ---------------------------------------------------------------------------
// K2: recurrent scan (unchanged from R4). 768 blocks x 3 waves.
// ---------------------------------------------------------------------------
__global__ __launch_bounds__(192)
void scan_kernel(const u16* __restrict__ xg,
    const float* __restrict__ u0, const float* __restrict__ u1,
    const float* __restrict__ u2, const float* __restrict__ u3,
    u16* __restrict__ comb)
{
  __shared__ u16 hl[2][1152];
  const int tid  = threadIdx.x;
  const int lane = tid & 63;
  const int wv   = tid >> 6;
  const int cl   = lane & 15;
  const int kg   = lane >> 4;
  const int W    = blockIdx.x;
  const int dir  = W / 192;
  const int g    = W - dir * 192;
  const int bb   = g / 3;
  const int rc   = (g - bb * 3) * 16 + cl;
  const bool vert = dir < 2;
  const bool bwd  = (dir & 1) != 0;

  const float* up = dir == 0 ? u0 : dir == 1 ? u1 : dir == 2 ? u2 : u3;

  const int tp0 = bwd ? 47 : 0;
  int px = vert ? (bb * 48 + tp0) * 48 + rc : (bb * 48 + rc) * 48 + tp0;
  const int dpx = (vert ? 48 : 1) * (bwd ? -1 : 1);
  const u16* xgd = xg + (size_t)dir * NPX * 192 + wv * 16 + kg * 4;

  short4v xb[4][4];
  #pragma unroll
  for (int s = 0; s < 4; ++s) {
    const u16* xp = xgd + (size_t)(px + s * dpx) * 192;
    #pragma unroll
    for (int q = 0; q < 4; ++q)
      xb[s][q] = *(const short4v*)(xp + q * 48);
  }

  short8 uf[4][2];
  #pragma unroll
  for (int q = 0; q < 4; ++q) {
    int n = q * 48 + wv * 16 + cl;
    {
      const float4* p = (const float4*)(up + n * 48 + kg * 8);
      uf[q][0] = cvt8(p[0], p[1]);
    }
    if (kg < 2) {
      const float4* p = (const float4*)(up + n * 48 + 32 + kg * 8);
      uf[q][1] = cvt8(p[0], p[1]);
    } else {
      short8 z = {}; uf[q][1] = z;
    }
  }

  u16* hz = &hl[0][0];
  for (int i = tid; i < 2304; i += 192) hz[i] = 0;
  __syncthreads();

  float c[4] = {0.f, 0.f, 0.f, 0.f};
  int cur = 0;
  u16* cb = comb + (size_t)dir * NPX * 48 + wv * 16 + kg * 4;

  for (int it = 0; it < 12; ++it) {
    #pragma unroll
    for (int u = 0; u < 4; ++u) {
      short8 hb0 = *(const short8*)&hl[cur][cl * 72 + kg * 8];
      short8 hb1 = *(const short8*)&hl[cur][cl * 72 + 32 + kg * 8];

      f32x4 acc[4];
      #pragma unroll
      for (int q = 0; q < 4; ++q) {
        f32x4 a;
        a[0] = bf2f((u16)xb[u][q][0]); a[1] = bf2f((u16)xb[u][q][1]);
        a[2] = bf2f((u16)xb[u][q][2]); a[3] = bf2f((u16)xb[u][q][3]);
        acc[q] = a;
      }
      {
        const u16* xp = xgd + (size_t)(px + 4 * dpx) * 192;
        #pragma unroll
        for (int q = 0; q < 4; ++q)
          xb[u][q] = *(const short4v*)(xp + q * 48);
      }
      #pragma unroll
      for (int q = 0; q < 4; ++q)
        acc[q] = __builtin_amdgcn_mfma_f32_16x16x32_bf16(uf[q][0], hb0, acc[q], 0, 0, 0);
      #pragma unroll
      for (int q = 0; q < 4; ++q)
        acc[q] = __builtin_amdgcn_mfma_f32_16x16x32_bf16(uf[q][1], hb1, acc[q], 0, 0, 0);

      short4v h4;
      #pragma unroll
      for (int r = 0; r < 4; ++r) {
        float ii = sigmoidf_fast(acc[0][r]);
        float ff = sigmoidf_fast(acc[1][r]);
        float gg = tanhf_fast(acc[2][r]);
        float oo = sigmoidf_fast(acc[3][r]);
        float cc = ff * c[r] + ii * gg;
        c[r] = cc;
        h4[r] = (short)f2bf(oo * tanhf_fast(cc));
      }
      *(short4v*)&hl[cur ^ 1][cl * 72 + wv * 16 + kg * 4] = h4;
      *(short4v*)(cb + (size_t)px * 48) = h4;
      __syncthreads();
      cur ^= 1;
      px += dpx;
    }
  }
}

// ---------------------------------------------------------------------------
// K3: projection (unchanged from R4).
// ---------------------------------------------------------------------------
__global__ __launch_bounds__(256)
void proj_kernel(const u16* __restrict__ comb,
                 const float* __restrict__ pw,
                 const float* __restrict__ pb,
                 float* __restrict__ out)
{
  __shared__ u16 al[12288];
  const int tid  = threadIdx.x;
  const int lane = tid & 63;
  const int wv   = tid >> 6;
  const int cl   = lane & 15;
  const int kg   = lane >> 4;
  const int pxb  = blockIdx.x * 64;

  #pragma unroll
  for (int i = 0; i < 6; ++i) {
    int ch = tid + 256 * i;
    int pxl = ch / 24;
    int k0  = (ch % 24) << 3;
    int d   = k0 / 48;
    short8 v = *(const short8*)(comb + ((size_t)d * NPX + pxb + pxl) * 48 + (k0 - d * 48));
    *(short8*)&al[(pxl * 192 + k0) ^ ((pxl & 7) << 3)] = v;
  }

  short8 wf[3][6];
  #pragma unroll
  for (int nt = 0; nt < 3; ++nt) {
    int n = wv * 48 + nt * 16 + cl;
    #pragma unroll
    for (int kk = 0; kk < 6; ++kk) {
      const float4* p = (const float4*)(pw + n * 192 + kk * 32 + kg * 8);
      wf[nt][kk] = cvt8(p[0], p[1]);
    }
  }
  f32x4 bv[3];
  #pragma unroll
  for (int nt = 0; nt < 3; ++nt)
    #pragma unroll
    for (int r = 0; r < 4; ++r)
      bv[nt][r] = pb[wv * 48 + nt * 16 + kg * 4 + r];

  __syncthreads();

  f32x4 acc[3][4];
  #pragma unroll
  for (int nt = 0; nt < 3; ++nt)
    #pragma unroll
    for (int mi = 0; mi < 4; ++mi) acc[nt][mi] = bv[nt];

  #pragma unroll
  for (int kk = 0; kk < 6; ++kk) {
    short8 bfr[4];
    #pragma unroll
    for (int mi = 0; mi < 4; ++mi) {
      int row = mi * 16 + cl;
      bfr[mi] = *(const short8*)&al[(row * 192 + kk * 32 + kg * 8) ^ ((row & 7) << 3)];
    }
    #pragma unroll
    for (int nt = 0; nt < 3; ++nt)
      #pragma unroll
      for (int mi = 0; mi < 4; ++mi)
        acc[nt][mi] = __builtin_amdgcn_mfma_f32_16x16x32_bf16(wf[nt][kk], bfr[mi], acc[nt][mi], 0, 0, 0);
  }

  #pragma unroll
  for (int nt = 0; nt < 3; ++nt)
    #pragma unroll
    for (int mi = 0; mi < 4; ++mi) {
      size_t o = (size_t)(pxb + mi * 16 + cl) * 192 + wv * 48 + nt * 16 + kg * 4;
      *(f32x4*)(out + o) = acc[nt][mi];
    }
}

extern "C" void kernel_launch(void* const* d_in, const int* in_sizes, int n_in,
                              void* d_out, int out_size, void* d_ws, size_t ws_size,
                              hipStream_t stream) {
  const float* x = (const float*)d_in[0];
  u16* xbf  = (u16*)d_ws;                              // 56.6 MB (tile-swizzled bf16 x)
  u16* xg   = (u16*)d_ws + (size_t)NTILES * 12288;     // 226.5 MB
  u16* comb = (u16*)d_ws;                              // overlays xbf (K1 done reading)

  xcvt_kernel<<<NTILES, 256, 0, stream>>>(x, xbf);

  xg_gemm_kernel<<<1152, 256, 0, stream>>>(
      xbf,
      (const float*)d_in[1], (const float*)d_in[5],
      (const float*)d_in[9], (const float*)d_in[13],
      (const float*)d_in[3],  (const float*)d_in[4],
      (const float*)d_in[7],  (const float*)d_in[8],
      (const float*)d_in[11], (const float*)d_in[12],
      (const float*)d_in[15], (const float*)d_in[16],
      xg);

  scan_kernel<<<768, 192, 0, stream>>>(
      xg,
      (const float*)d_in[2], (const float*)d_in[6],
      (const float*)d_in[10], (const float*)d_in[14],
      comb);

  proj_kernel<<<2304, 256, 0, stream>>>(
      comb, (const float*)d_in[17], (const float*)d_in[18], (float*)d_out);
}

// Round 6
// 217.623 us; speedup vs baseline: 2.4188x; 1.4518x over previous
//
#include <hip/hip_runtime.h>

typedef short short8 __attribute__((ext_vector_type(8)));
typedef short short4v __attribute__((ext_vector_type(4)));
typedef float f32x4 __attribute__((ext_vector_type(4)));
typedef unsigned short u16;

__device__ __forceinline__ u16 f2bf(float f) {
  unsigned int u = __builtin_bit_cast(unsigned int, f);
  u = (u + 0x7FFFu + ((u >> 16) & 1u)) >> 16;
  return (u16)u;
}
__device__ __forceinline__ short8 cvt8(float4 a, float4 b) {
  short8 v;
  v[0] = (short)f2bf(a.x); v[1] = (short)f2bf(a.y);
  v[2] = (short)f2bf(a.z); v[3] = (short)f2bf(a.w);
  v[4] = (short)f2bf(b.x); v[5] = (short)f2bf(b.y);
  v[6] = (short)f2bf(b.z); v[7] = (short)f2bf(b.w);
  return v;
}
__device__ __forceinline__ float sigmoidf_fast(float x) {
  return __builtin_amdgcn_rcpf(1.0f + __expf(-x));
}
__device__ __forceinline__ float tanhf_fast(float x) {
  return 1.0f - 2.0f * __builtin_amdgcn_rcpf(1.0f + __expf(2.0f * x));
}

#define NPX 147456  // 64*48*48

// ---------------------------------------------------------------------------
// K0: x fp32 -> xbf bf16, plain row-major. 113 MB read + 57 MB write.
// ---------------------------------------------------------------------------
__global__ __launch_bounds__(256)
void xcvt_kernel(const float* __restrict__ x, u16* __restrict__ xbf)
{
  size_t c = ((size_t)blockIdx.x * 256 + threadIdx.x) * 8;
  const float4* p = (const float4*)(x + c);
  *(short8*)(xbf + c) = cvt8(p[0], p[1]);
}

// ---------------------------------------------------------------------------
// K2: FUSED scan. 768 blocks x 3 waves; block owns 16 seqs of one direction.
// Per step: gates = bias + Wih@x_t (24 MFMA, x streamed from L3-resident xbf,
// depth-2 reg prefetch) + Whh@h (8 MFMA, h double-buffered LDS). Wave wv owns
// hd-slice [16wv,16wv+16) = gate tiles {wv,3+wv,6+wv,9+wv}; Wih+Whh frags in
// registers. No xg intermediate. 1 barrier/step.
// ---------------------------------------------------------------------------
__global__ __launch_bounds__(192)
void fused_scan_kernel(const u16* __restrict__ xbf,
    const float* __restrict__ wi0, const float* __restrict__ wi1,
    const float* __restrict__ wi2, const float* __restrict__ wi3,
    const float* __restrict__ u0, const float* __restrict__ u1,
    const float* __restrict__ u2, const float* __restrict__ u3,
    const float* __restrict__ bi0, const float* __restrict__ bh0,
    const float* __restrict__ bi1, const float* __restrict__ bh1,
    const float* __restrict__ bi2, const float* __restrict__ bh2,
    const float* __restrict__ bi3, const float* __restrict__ bh3,
    u16* __restrict__ comb)
{
  __shared__ u16 hl[2][1152];          // [16 seq][72] (48 h + 24 zero pad)
  const int tid  = threadIdx.x;
  const int lane = tid & 63;
  const int wv   = tid >> 6;           // 0..2 -> hd slice
  const int cl   = lane & 15;
  const int kg   = lane >> 4;
  const int W    = blockIdx.x;         // 0..767
  const int dir  = W / 192;
  const int g    = W - dir * 192;
  const int bb   = g / 3;
  const int rc   = (g - bb * 3) * 16 + cl;
  const bool vert = dir < 2;
  const bool bwd  = (dir & 1) != 0;

  const float* wp  = dir == 0 ? wi0 : dir == 1 ? wi1 : dir == 2 ? wi2 : wi3;
  const float* up  = dir == 0 ? u0  : dir == 1 ? u1  : dir == 2 ? u2  : u3;
  const float* bip = dir == 0 ? bi0 : dir == 1 ? bi1 : dir == 2 ? bi2 : bi3;
  const float* bhp = dir == 0 ? bh0 : dir == 1 ? bh1 : dir == 2 ? bh2 : bh3;

  const int tp0 = bwd ? 47 : 0;
  int px = vert ? (bb * 48 + tp0) * 48 + rc : (bb * 48 + rc) * 48 + tp0;
  const int dpx = (vert ? 48 : 1) * (bwd ? -1 : 1);

  // ---- x-frag prefetch ring (depth 2), issued before weight setup
  short8 xfA[6], xfB[6];
  {
    const u16* xp = xbf + (size_t)px * 192 + kg * 8;
    #pragma unroll
    for (int kk = 0; kk < 6; ++kk) xfA[kk] = *(const short8*)(xp + kk * 32);
    const u16* xq = xbf + (size_t)(px + dpx) * 192 + kg * 8;
    #pragma unroll
    for (int kk = 0; kk < 6; ++kk) xfB[kk] = *(const short8*)(xq + kk * 32);
  }

  // ---- Wih fragments (A-operand): gate tile q -> rows q*48+wv*16+cl
  short8 wf[4][6];
  #pragma unroll
  for (int q = 0; q < 4; ++q) {
    int n = q * 48 + wv * 16 + cl;
    #pragma unroll
    for (int kk = 0; kk < 6; ++kk) {
      const float4* p = (const float4*)(wp + n * 192 + kk * 32 + kg * 8);
      wf[q][kk] = cvt8(p[0], p[1]);
    }
  }
  // ---- Whh fragments, K padded 48->64 (zeros for k>=48)
  short8 uf[4][2];
  #pragma unroll
  for (int q = 0; q < 4; ++q) {
    int n = q * 48 + wv * 16 + cl;
    {
      const float4* p = (const float4*)(up + n * 48 + kg * 8);
      uf[q][0] = cvt8(p[0], p[1]);
    }
    if (kg < 2) {
      const float4* p = (const float4*)(up + n * 48 + 32 + kg * 8);
      uf[q][1] = cvt8(p[0], p[1]);
    } else {
      short8 z = {}; uf[q][1] = z;
    }
  }
  // ---- bias (acc init): D row = q*48 + wv*16 + kg*4 + r
  f32x4 bv[4];
  #pragma unroll
  for (int q = 0; q < 4; ++q)
    #pragma unroll
    for (int r = 0; r < 4; ++r) {
      int n = q * 48 + wv * 16 + kg * 4 + r;
      bv[q][r] = bip[n] + bhp[n];
    }

  // zero both h buffers (t=0 sees h=0; pads stay zero)
  u16* hz = &hl[0][0];
  for (int i = tid; i < 2304; i += 192) hz[i] = 0;
  __syncthreads();

  float c[4] = {0.f, 0.f, 0.f, 0.f};
  int cur = 0;
  u16* cb = comb + (size_t)dir * NPX * 48 + wv * 16 + kg * 4;

  const u16* xk = xbf + kg * 8;

  for (int it = 0; it < 24; ++it) {
    #pragma unroll
    for (int half = 0; half < 2; ++half) {
      short8* xf = half ? xfB : xfA;

      // acc = bias + Wih @ x_t  (independent of h -> fills MFMA pipe early)
      f32x4 acc[4];
      #pragma unroll
      for (int q = 0; q < 4; ++q) acc[q] = bv[q];
      #pragma unroll
      for (int kk = 0; kk < 6; ++kk)
        #pragma unroll
        for (int q = 0; q < 4; ++q)
          acc[q] = __builtin_amdgcn_mfma_f32_16x16x32_bf16(wf[q][kk], xf[kk], acc[q], 0, 0, 0);

      // refill this ring slot for t+2 (clamped at sequence ends)
      {
        int pp = px + 2 * dpx;
        pp = (pp < 0 || pp >= NPX) ? 0 : pp;
        const u16* xp = xk + (size_t)pp * 192;
        #pragma unroll
        for (int kk = 0; kk < 6; ++kk) xf[kk] = *(const short8*)(xp + kk * 32);
      }

      // + Whh @ h
      short8 hb0 = *(const short8*)&hl[cur][cl * 72 + kg * 8];
      short8 hb1 = *(const short8*)&hl[cur][cl * 72 + 32 + kg * 8];
      #pragma unroll
      for (int q = 0; q < 4; ++q)
        acc[q] = __builtin_amdgcn_mfma_f32_16x16x32_bf16(uf[q][0], hb0, acc[q], 0, 0, 0);
      #pragma unroll
      for (int q = 0; q < 4; ++q)
        acc[q] = __builtin_amdgcn_mfma_f32_16x16x32_bf16(uf[q][1], hb1, acc[q], 0, 0, 0);

      // epilogue: lane -> seq=cl, hd = wv*16 + kg*4 + r
      short4v h4;
      #pragma unroll
      for (int r = 0; r < 4; ++r) {
        float ii = sigmoidf_fast(acc[0][r]);
        float ff = sigmoidf_fast(acc[1][r]);
        float gg = tanhf_fast(acc[2][r]);
        float oo = sigmoidf_fast(acc[3][r]);
        float cc = ff * c[r] + ii * gg;
        c[r] = cc;
        h4[r] = (short)f2bf(oo * tanhf_fast(cc));
      }
      *(short4v*)&hl[cur ^ 1][cl * 72 + wv * 16 + kg * 4] = h4;
      *(short4v*)(cb + (size_t)px * 48) = h4;
      __syncthreads();
      cur ^= 1;
      px += dpx;
    }
  }
}

// ---------------------------------------------------------------------------
// K3: out[px][c] = comb4[px][:] @ proj_w[c][:] + proj_b[c], fp32. (unchanged)
// ---------------------------------------------------------------------------
__global__ __launch_bounds__(256)
void proj_kernel(const u16* __restrict__ comb,
                 const float* __restrict__ pw,
                 const float* __restrict__ pb,
                 float* __restrict__ out)
{
  __shared__ u16 al[12288];
  const int tid  = threadIdx.x;
  const int lane = tid & 63;
  const int wv   = tid >> 6;
  const int cl   = lane & 15;
  const int kg   = lane >> 4;
  const int pxb  = blockIdx.x * 64;

  #pragma unroll
  for (int i = 0; i < 6; ++i) {
    int ch = tid + 256 * i;
    int pxl = ch / 24;
    int k0  = (ch % 24) << 3;
    int d   = k0 / 48;
    short8 v = *(const short8*)(comb + ((size_t)d * NPX + pxb + pxl) * 48 + (k0 - d * 48));
    *(short8*)&al[(pxl * 192 + k0) ^ ((pxl & 7) << 3)] = v;
  }

  short8 wf[3][6];
  #pragma unroll
  for (int nt = 0; nt < 3; ++nt) {
    int n = wv * 48 + nt * 16 + cl;
    #pragma unroll
    for (int kk = 0; kk < 6; ++kk) {
      const float4* p = (const float4*)(pw + n * 192 + kk * 32 + kg * 8);
      wf[nt][kk] = cvt8(p[0], p[1]);
    }
  }
  f32x4 bv[3];
  #pragma unroll
  for (int nt = 0; nt < 3; ++nt)
    #pragma unroll
    for (int r = 0; r < 4; ++r)
      bv[nt][r] = pb[wv * 48 + nt * 16 + kg * 4 + r];

  __syncthreads();

  f32x4 acc[3][4];
  #pragma unroll
  for (int nt = 0; nt < 3; ++nt)
    #pragma unroll
    for (int mi = 0; mi < 4; ++mi) acc[nt][mi] = bv[nt];

  #pragma unroll
  for (int kk = 0; kk < 6; ++kk) {
    short8 bfr[4];
    #pragma unroll
    for (int mi = 0; mi < 4; ++mi) {
      int row = mi * 16 + cl;
      bfr[mi] = *(const short8*)&al[(row * 192 + kk * 32 + kg * 8) ^ ((row & 7) << 3)];
    }
    #pragma unroll
    for (int nt = 0; nt < 3; ++nt)
      #pragma unroll
      for (int mi = 0; mi < 4; ++mi)
        acc[nt][mi] = __builtin_amdgcn_mfma_f32_16x16x32_bf16(wf[nt][kk], bfr[mi], acc[nt][mi], 0, 0, 0);
  }

  #pragma unroll
  for (int nt = 0; nt < 3; ++nt)
    #pragma unroll
    for (int mi = 0; mi < 4; ++mi) {
      size_t o = (size_t)(pxb + mi * 16 + cl) * 192 + wv * 48 + nt * 16 + kg * 4;
      *(f32x4*)(out + o) = acc[nt][mi];
    }
}

extern "C" void kernel_launch(void* const* d_in, const int* in_sizes, int n_in,
                              void* d_out, int out_size, void* d_ws, size_t ws_size,
                              hipStream_t stream) {
  const float* x = (const float*)d_in[0];
  u16* xbf  = (u16*)d_ws;                              // 56.6 MB row-major bf16 x
  u16* comb = (u16*)d_ws + (size_t)NPX * 192;          // 56.6 MB

  xcvt_kernel<<<13824, 256, 0, stream>>>(x, xbf);

  fused_scan_kernel<<<768, 192, 0, stream>>>(
      xbf,
      (const float*)d_in[1], (const float*)d_in[5],
      (const float*)d_in[9], (const float*)d_in[13],
      (const float*)d_in[2], (const float*)d_in[6],
      (const float*)d_in[10], (const float*)d_in[14],
      (const float*)d_in[3],  (const float*)d_in[4],
      (const float*)d_in[7],  (const float*)d_in[8],
      (const float*)d_in[11], (const float*)d_in[12],
      (const float*)d_in[15], (const float*)d_in[16],
      comb);

  proj_kernel<<<2304, 256, 0, stream>>>(
      comb, (const float*)d_in[17], (const float*)d_in[18], (float*)d_out);
}